// Round 8
// baseline (808.770 us; speedup 1.0000x reference)
//
#include <hip/hip_runtime.h>
#include <stdint.h>

#define IN_C 128
#define OUT_C 64
#define NEG_SLOPE 0.2f
#define RB 256      // blocks in coarse-partition kernels
#define RBINS 512   // coarse bins (node>>8, node<131072)
#define STAGE 8192  // per-bucket LDS staging capacity
#define NGH (RBINS * RB)       // 131072 (tgt histogram)
#define NGHS (RBINS * RBINS)   // 262144 (src histogram)
#define KC 16                  // gemm k-chunk
#define GROWS 128              // gemm row tile

typedef unsigned int u32;
typedef unsigned long long u64;

// ---------------- helpers ----------------
__device__ __forceinline__ u32 fenc(float f) {
  u32 u = __float_as_uint(f);
  return (u & 0x80000000u) ? ~u : (u | 0x80000000u);
}
__device__ __forceinline__ u64 key64(float v, int i) {
  return (((u64)fenc(v)) << 32) | (u64)(0xffffffffu - (u32)i);
}

// ---------------- h = x @ W + fused ai/aj epilogue ----------------
// 128-row tile, 128 threads, 8x8/thread. KC=16. LDS 40KB -> 4 blocks/CU; grid 782.
// sx[k*128+row] identity layout: staging writes bank=lane%32 (2-way, free);
// b128 reads at rg*8 -> quads {2rg,2rg+1} (2-way, free). Staging global loads: 64B/row contiguous.
__global__ __launch_bounds__(128) void k_gemm(const float* __restrict__ x,
                                              const float* __restrict__ w,
                                              const float* __restrict__ att,
                                              float* __restrict__ h,
                                              float* __restrict__ ai, float* __restrict__ aj,
                                              int N) {
  __shared__ float sw[IN_C * OUT_C];   // 32 KB
  __shared__ float sx[KC * GROWS];     // 8 KB
  int tid = threadIdx.x;
  int rbase = blockIdx.x * GROWS;

  for (int i = tid; i < (IN_C * OUT_C) / 4; i += 128)
    ((float4*)sw)[i] = ((const float4*)w)[i];

  int cg = tid & 7, rg = tid >> 3;     // rg 0..15, 8 rows each
  int c0 = cg * 8, r0 = rg * 8;
  float acc[8][8];
#pragma unroll
  for (int i = 0; i < 8; i++)
#pragma unroll
    for (int j = 0; j < 8; j++) acc[i][j] = 0.f;

  for (int kb = 0; kb < IN_C; kb += KC) {
    __syncthreads();
    {
      int grow = rbase + tid;
      float4 v0 = make_float4(0.f,0.f,0.f,0.f), v1 = v0, v2 = v0, v3 = v0;
      if (grow < N) {
        const float4* xp = (const float4*)&x[(size_t)grow * IN_C + kb];
        v0 = xp[0]; v1 = xp[1]; v2 = xp[2]; v3 = xp[3];
      }
      sx[ 0*GROWS + tid] = v0.x; sx[ 1*GROWS + tid] = v0.y;
      sx[ 2*GROWS + tid] = v0.z; sx[ 3*GROWS + tid] = v0.w;
      sx[ 4*GROWS + tid] = v1.x; sx[ 5*GROWS + tid] = v1.y;
      sx[ 6*GROWS + tid] = v1.z; sx[ 7*GROWS + tid] = v1.w;
      sx[ 8*GROWS + tid] = v2.x; sx[ 9*GROWS + tid] = v2.y;
      sx[10*GROWS + tid] = v2.z; sx[11*GROWS + tid] = v2.w;
      sx[12*GROWS + tid] = v3.x; sx[13*GROWS + tid] = v3.y;
      sx[14*GROWS + tid] = v3.z; sx[15*GROWS + tid] = v3.w;
    }
    __syncthreads();
#pragma unroll
    for (int kl = 0; kl < KC; ++kl) {
      int kg = kb + kl;
      float xr[8], wv[8];
      *(float4*)&xr[0] = *(const float4*)&sx[kl * GROWS + r0];
      *(float4*)&xr[4] = *(const float4*)&sx[kl * GROWS + r0 + 4];
      *(float4*)&wv[0] = *(const float4*)&sw[kg * OUT_C + c0];
      *(float4*)&wv[4] = *(const float4*)&sw[kg * OUT_C + c0 + 4];
#pragma unroll
      for (int i = 0; i < 8; ++i)
#pragma unroll
        for (int j = 0; j < 8; ++j)
          acc[i][j] += xr[i] * wv[j];
    }
  }

  float pi[8], pj[8];
#pragma unroll
  for (int i = 0; i < 8; ++i) { pi[i] = 0.f; pj[i] = 0.f; }
#pragma unroll
  for (int j = 0; j < 8; ++j) {
    float a0 = att[c0 + j], a1 = att[OUT_C + c0 + j];
#pragma unroll
    for (int i = 0; i < 8; ++i) {
      pi[i] += acc[i][j] * a0;
      pj[i] += acc[i][j] * a1;
    }
  }
#pragma unroll
  for (int o = 1; o < 8; o <<= 1) {
#pragma unroll
    for (int i = 0; i < 8; ++i) {
      pi[i] += __shfl_xor(pi[i], o);
      pj[i] += __shfl_xor(pj[i], o);
    }
  }
#pragma unroll
  for (int i = 0; i < 8; ++i) {
    int row = rbase + r0 + i;
    if (row < N) {
      *(float4*)&h[(size_t)row * OUT_C + c0]     = make_float4(acc[i][0], acc[i][1], acc[i][2], acc[i][3]);
      *(float4*)&h[(size_t)row * OUT_C + c0 + 4] = make_float4(acc[i][4], acc[i][5], acc[i][6], acc[i][7]);
      if (cg == 0) { ai[row] = pi[i]; aj[row] = pj[i]; }
    }
  }
}

// ---------------- coarse hist by tgt>>8 + fused state init (select + scan state) ----------------
__global__ __launch_bounds__(256) void k_rhist_t(const int* __restrict__ tgt,
                                                 int E, int EN, int chunk, u32* __restrict__ gh,
                                                 u32* __restrict__ hist8, u32* __restrict__ done,
                                                 u32* __restrict__ sel, u32* __restrict__ cnt, u32 k,
                                                 u64* __restrict__ stateT, u64* __restrict__ stateS,
                                                 u32* __restrict__ tickets) {
  __shared__ u32 lh[RBINS];
  int tid = threadIdx.x, b = blockIdx.x;
  if (b == 0) {   // fused init — completes before any consumer kernel launches
    for (int i = tid; i < 2048; i += 256) hist8[i] = 0u;
    for (int i = tid; i < 512;  i += 256) stateT[i] = 0ull;
    for (int i = tid; i < 1024; i += 256) stateS[i] = 0ull;
    if (tid < 8) { done[tid] = 0u; cnt[tid] = 0u; }
    if (tid < 2) tickets[tid] = 0u;
    if (tid == 0) { sel[0] = 0u; sel[1] = 0u; sel[2] = k; sel[3] = 0u; }
  }
  for (int d = tid; d < RBINS; d += 256) lh[d] = 0u;
  __syncthreads();
  int lo = b * chunk, hi = min(lo + chunk, EN);
  for (int e = lo + tid; e < hi; e += 256) {
    int t = (e < E) ? tgt[e] : e - E;
    atomicAdd(&lh[((u32)t) >> 8], 1u);
  }
  __syncthreads();
  for (int d = tid; d < RBINS; d += 256) gh[d * RB + b] = lh[d];
}

// ---------------- single-kernel exclusive scan: decoupled lookback ----------------
// ticket order = start order -> earlier tickets always scheduled -> no deadlock.
__global__ __launch_bounds__(256) void k_scan(u32* __restrict__ data, int n,
                                              u32* __restrict__ ticket, u64* __restrict__ state) {
  __shared__ u32 s[256];
  __shared__ u32 sticket;
  __shared__ u32 sprefix;
  int tid = threadIdx.x;
  if (tid == 0)
    sticket = __hip_atomic_fetch_add(ticket, 1u, __ATOMIC_RELAXED, __HIP_MEMORY_SCOPE_AGENT);
  __syncthreads();
  u32 b = sticket;
  int i = (int)b * 256 + tid;
  u32 v = (i < n) ? data[i] : 0u;
  s[tid] = v;
  __syncthreads();
  for (int o = 1; o < 256; o <<= 1) {
    u32 t = (tid >= o) ? s[tid - o] : 0u;
    __syncthreads();
    s[tid] += t;
    __syncthreads();
  }
  if (tid == 0) {
    u32 total = s[255];
    __hip_atomic_store(&state[b], (1ull << 32) | (u64)total, __ATOMIC_RELEASE,
                       __HIP_MEMORY_SCOPE_AGENT);
    u32 pref = 0;
    int j = (int)b - 1;
    while (j >= 0) {
      u64 st;
      do {
        st = __hip_atomic_load(&state[j], __ATOMIC_ACQUIRE, __HIP_MEMORY_SCOPE_AGENT);
      } while ((st >> 32) == 0ull);
      pref += (u32)st;
      if ((st >> 32) == 2ull) break;
      --j;
    }
    __hip_atomic_store(&state[b], (2ull << 32) | (u64)(pref + total), __ATOMIC_RELEASE,
                       __HIP_MEMORY_SCOPE_AGENT);
    sprefix = pref;
  }
  __syncthreads();
  if (i < n) data[i] = sprefix + s[tid] - v;
}

// ---------------- coarse scatter by tgt>>8: u32 items ((tgt&255)<<24 | src) ----------------
__global__ __launch_bounds__(256) void k_rscatter_t(const int* __restrict__ src, const int* __restrict__ tgt,
                                                    int E, int EN, int chunk,
                                                    const u32* __restrict__ gh, u32* __restrict__ bufB) {
  __shared__ u32 cnt[RBINS];
  int tid = threadIdx.x, b = blockIdx.x;
  for (int d = tid; d < RBINS; d += 256) cnt[d] = gh[d * RB + b];
  __syncthreads();
  int lo = b * chunk, hi = min(lo + chunk, EN);
  for (int e = lo + tid; e < hi; e += 256) {
    int s, t;
    if (e < E) { s = src[e]; t = tgt[e]; } else { s = t = e - E; }
    u32 p = atomicAdd(&cnt[((u32)t) >> 8], 1u);
    bufB[p] = (((u32)t & 255u) << 24) | (u32)s;
  }
}

// ---------------- fine partition + CSR offsets + fused src>>8 hist + FUSED SOFTMAX ----
__global__ __launch_bounds__(256) void k_rpass2(const u32* __restrict__ in, u32* __restrict__ out,
                                                const u32* __restrict__ gh, u32* __restrict__ ghs,
                                                u32* __restrict__ offT,
                                                const float* __restrict__ ai, const float* __restrict__ aj,
                                                float* __restrict__ alpha,
                                                int N, int EN) {
  __shared__ u32 hist[256];
  __shared__ u32 sc[256];
  __shared__ u32 lhs[RBINS];
  __shared__ u32 stage[STAGE];
  int tid = threadIdx.x, d = blockIdx.x;
  u32 start = gh[d * RB];
  u32 end = (d < RBINS - 1) ? gh[(d + 1) * RB] : (u32)EN;
  int sz = (int)(end - start);
  hist[tid] = 0u;
  for (int dd = tid; dd < RBINS; dd += 256) lhs[dd] = 0u;
  __syncthreads();
  for (u32 p = start + tid; p < end; p += 256) {
    u32 it = in[p];
    atomicAdd(&hist[it >> 24], 1u);
    atomicAdd(&lhs[(it & 0xffffffu) >> 8], 1u);
  }
  __syncthreads();
  for (int dd = tid; dd < RBINS; dd += 256) ghs[dd * RBINS + d] = lhs[dd];
  u32 hv = hist[tid];
  sc[tid] = hv;
  __syncthreads();
  for (int o = 1; o < 256; o <<= 1) {
    u32 t = (tid >= o) ? sc[tid - o] : 0u;
    __syncthreads();
    sc[tid] += t;
    __syncthreads();
  }
  u32 excl = sc[tid] - hv;
  int node = (d << 8) + tid;
  if (node < N) offT[node] = start + excl;
  if (node == 0) offT[N] = (u32)EN;
  hist[tid] = excl;
  __syncthreads();
  bool staged = (sz <= STAGE);
  for (u32 p = start + tid; p < end; p += 256) {
    u32 it = in[p];
    u32 lp = atomicAdd(&hist[it >> 24], 1u);
    if (staged) stage[lp] = it;
    else out[start + lp] = it;
  }
  __syncthreads();
  if (staged)
    for (int i = tid; i < sz; i += 256) out[start + i] = stage[i];
  __syncthreads();
  if (node < N) {
    int lb = (tid > 0) ? (int)sc[tid - 1] : 0;
    int le = (int)sc[tid];
    float an = ai[node];
    float mx = -1e30f;
    for (int i = lb; i < le; ++i) {
      u32 it = staged ? stage[i] : out[start + i];
      float a = an + aj[it & 0xffffffu];
      a = a > 0.f ? a : NEG_SLOPE * a;
      mx = fmaxf(mx, a);
      if (staged) stage[i] = __float_as_uint(a);
    }
    float sm = 0.f;
    for (int i = lb; i < le; ++i) {
      float a;
      if (staged) a = __uint_as_float(stage[i]);
      else {
        u32 it = out[start + i];
        a = an + aj[it & 0xffffffu];
        a = a > 0.f ? a : NEG_SLOPE * a;
      }
      float v = expf(a - mx);
      sm += v;
      if (staged) stage[i] = __float_as_uint(v);
      else alpha[start + i] = v;
    }
    float inv = 1.f / (sm + 1e-16f);
    for (int i = lb; i < le; ++i) {
      float v = staged ? __uint_as_float(stage[i]) : alpha[start + i];
      alpha[start + i] = v * inv;
    }
  }
}

// ---------------- scatter by src>>8 over the SAME per-bucket ranges as k_rpass2 ----------------
__global__ __launch_bounds__(256) void k_rscatter_s(const u32* __restrict__ csr,
                                                    const float* __restrict__ alpha,
                                                    const u32* __restrict__ gh, const u32* __restrict__ ghs,
                                                    u64* __restrict__ bufB, int EN) {
  __shared__ u32 cnt[RBINS];
  int tid = threadIdx.x, d = blockIdx.x;
  for (int dd = tid; dd < RBINS; dd += 256) cnt[dd] = ghs[dd * RBINS + d];
  __syncthreads();
  u32 start = gh[d * RB];
  u32 end = (d < RBINS - 1) ? gh[(d + 1) * RB] : (u32)EN;
  for (u32 e = start + tid; e < end; e += 256) {
    u32 s = csr[e] & 0xffffffu;
    u32 p = atomicAdd(&cnt[s >> 8], 1u);
    bufB[p] = (((u64)(s & 255u)) << 32) | __float_as_uint(alpha[e]);
  }
}

// ---------------- per-bucket alpha_sum accumulation (LDS fp bins) ----------------
__global__ __launch_bounds__(256) void k_asum_acc(const u64* __restrict__ bufB,
                                                  const u32* __restrict__ ghs,
                                                  float* __restrict__ asum, int N, int EN) {
  __shared__ float sums[256];
  int tid = threadIdx.x, d = blockIdx.x;
  u32 start = ghs[d * RBINS];
  u32 end = (d < RBINS - 1) ? ghs[(d + 1) * RBINS] : (u32)EN;
  sums[tid] = 0.f;
  __syncthreads();
  for (u32 p = start + tid; p < end; p += 256) {
    u64 it = bufB[p];
    atomicAdd(&sums[(u32)(it >> 32)], __uint_as_float((u32)it));
  }
  __syncthreads();
  int node = d * 256 + tid;
  if (node < N) asum[node] = sums[tid];
}

// ---------------- fused radix-select pass: hist + append + last-block pick ----------------
__global__ __launch_bounds__(256) void k_histpick(const float* __restrict__ asum,
                                                  const u32* __restrict__ list_in, const u32* __restrict__ cnt_in,
                                                  u32* __restrict__ list_out, u32* __restrict__ cnt_out,
                                                  u32* __restrict__ hist8, u32* __restrict__ done,
                                                  u32* __restrict__ sel, int N, int pass, int nblk) {
  __shared__ u32 lh[256];
  __shared__ u32 sres;
  __shared__ u32 s[256];
  int tid = threadIdx.x;
  lh[tid] = 0u;
  __syncthreads();
  u64 prefix = ((const u64*)sel)[0];
  int shift = 56 - 8 * pass;
  int n = list_in ? (int)*cnt_in : N;
  int i = blockIdx.x * 256 + tid;
  if (i < n) {
    int idx = list_in ? (int)list_in[i] : i;
    u64 k = key64(asum[idx], idx);
    bool ok = (pass == 0) || ((k >> (shift + 8)) == prefix);
    if (ok) {
      atomicAdd(&lh[(u32)(k >> shift) & 255u], 1u);
      if (list_out) {
        u32 p = atomicAdd(cnt_out, 1u);
        list_out[p] = (u32)idx;
      }
    }
  }
  __syncthreads();
  if (lh[tid]) atomicAdd(&hist8[pass * 256 + tid], lh[tid]);
  __syncthreads();
  if (tid == 0)
    sres = __hip_atomic_fetch_add(&done[pass], 1u, __ATOMIC_ACQ_REL, __HIP_MEMORY_SCOPE_AGENT);
  __syncthreads();
  if (sres == (u32)(nblk - 1)) {
    u32 krem = sel[2];
    u32 hv = __hip_atomic_load(&hist8[pass * 256 + (255 - tid)], __ATOMIC_RELAXED,
                               __HIP_MEMORY_SCOPE_AGENT);
    s[tid] = hv;
    __syncthreads();
    for (int o = 1; o < 256; o <<= 1) {
      u32 t = (tid >= o) ? s[tid - o] : 0u;
      __syncthreads();
      s[tid] += t;
      __syncthreads();
    }
    u32 cum = s[tid], prev = (tid > 0) ? s[tid - 1] : 0u;
    if (cum >= krem && prev < krem) {
      int dsel = 255 - tid;
      ((u64*)sel)[0] = (prefix << 8) | (u64)(u32)dsel;
      sel[2] = krem - prev;
    }
  }
}

// ---------------- finish select: fenc fixed after 4 passes; rank-select index ties ----------------
__global__ __launch_bounds__(256) void k_finish(const float* __restrict__ asum,
                                                const u32* __restrict__ list, const u32* __restrict__ cntp,
                                                u32* __restrict__ sel) {
  __shared__ u64 keys[2048];
  __shared__ u32 cc;
  int tid = threadIdx.x;
  if (tid == 0) cc = 0u;
  __syncthreads();
  int n = (int)*cntp;
  u32 fsel = (u32)((const u64*)sel)[0];
  u32 krem = sel[2];
  for (int i = tid; i < n; i += 256) {
    int idx = (int)list[i];
    u64 k = key64(asum[idx], idx);
    if ((u32)(k >> 32) == fsel) {
      u32 p = atomicAdd(&cc, 1u);
      if (p < 2048) keys[p] = k;
    }
  }
  __syncthreads();
  int C = (int)min(cc, 2048u);
  for (int i = tid; i < C; i += 256) {
    u64 k = keys[i];
    u32 rank = 0;
    for (int j = 0; j < C; ++j)
      if (keys[j] > k) rank++;
    if (rank == krem - 1) ((u64*)sel)[0] = k;
  }
}

// ---------------- node mask ----------------
__global__ __launch_bounds__(256) void k_node_mask(const float* __restrict__ asum,
                                                   const u32* __restrict__ sel,
                                                   u32* __restrict__ nm,
                                                   float* __restrict__ out_node, int N) {
  int i = blockIdx.x * 256 + threadIdx.x;
  if (i >= N) return;
  u64 T = ((const u64*)sel)[0];
  bool m = key64(asum[i], i) >= T;
  nm[i] = m ? 1u : 0u;
  out_node[i] = m ? 1.f : 0.f;
}

// ---------------- fused: raw-order edge mask + CSR-order premasked (src,alpha) pairs ----------------
__global__ __launch_bounds__(256) void k_mask(const int* __restrict__ src, const int* __restrict__ tgt,
                                              const u32* __restrict__ nm,
                                              const u32* __restrict__ csr, const float* __restrict__ alpha,
                                              float* __restrict__ out_edge, u64* __restrict__ pair,
                                              int E, int EN) {
  int e = blockIdx.x * 256 + threadIdx.x;
  if (e >= EN) return;
  int s, t;
  if (e < E) { s = src[e]; t = tgt[e]; } else { s = t = e - E; }
  out_edge[e] = (nm[s] && nm[t]) ? 1.f : 0.f;
  u32 sp = csr[e] & 0xffffffu;
  u32 ab = nm[sp] ? __float_as_uint(alpha[e]) : 0u;
  pair[e] = (((u64)sp) << 32) | ab;
}

// ---------------- aggregate: branchless, 2 nodes/wave, 8-deep pipeline ----------------
__global__ __launch_bounds__(256) void k_aggregate(const u32* __restrict__ off,
                                                   const u64* __restrict__ pair,
                                                   const float* __restrict__ h,
                                                   const u32* __restrict__ nm,
                                                   float* __restrict__ out, int N) {
  int node = blockIdx.x * 8 + (threadIdx.x >> 5);
  int sub = threadIdx.x & 31;
  int g = sub >> 4;         // 2 edge groups
  int c = sub & 15;         // channel quad
  if (node >= N) return;
  float4 acc = make_float4(0.f, 0.f, 0.f, 0.f);
  if (nm[node]) {
    u32 b = off[node], e2 = off[node + 1];
    for (u32 p0 = b; p0 < e2; p0 += 16) {
      u64 pr[8];
      float av[8];
      u32 sv[8];
#pragma unroll
      for (int q = 0; q < 8; ++q) {
        u32 p = p0 + q * 2 + (u32)g;
        bool ok = p < e2;
        pr[q] = pair[ok ? p : b];
        av[q] = ok ? __uint_as_float((u32)pr[q]) : 0.f;
        sv[q] = (u32)(pr[q] >> 32);
      }
      float4 hv[8];
#pragma unroll
      for (int q = 0; q < 8; ++q)
        hv[q] = *(const float4*)&h[(size_t)sv[q] * OUT_C + c * 4];
#pragma unroll
      for (int q = 0; q < 8; ++q) {
        acc.x += av[q] * hv[q].x;
        acc.y += av[q] * hv[q].y;
        acc.z += av[q] * hv[q].z;
        acc.w += av[q] * hv[q].w;
      }
    }
    acc.x += __shfl_xor(acc.x, 16);
    acc.y += __shfl_xor(acc.y, 16);
    acc.z += __shfl_xor(acc.z, 16);
    acc.w += __shfl_xor(acc.w, 16);
  }
  if (g == 0)
    *(float4*)&out[(size_t)node * OUT_C + c * 4] = acc;
}

// ---------------- launch ----------------
extern "C" void kernel_launch(void* const* d_in, const int* in_sizes, int n_in,
                              void* d_out, int out_size, void* d_ws, size_t ws_size,
                              hipStream_t stream) {
  const float* x   = (const float*)d_in[0];
  const float* w   = (const float*)d_in[1];
  const float* att = (const float*)d_in[2];
  const int*   ei  = (const int*)d_in[3];

  int N = in_sizes[0] / IN_C;
  int E = in_sizes[3] / 2;
  int EN = E + N;
  const int* src = ei;
  const int* tgt = ei + E;

  float* out      = (float*)d_out;
  float* out_edge = out + (size_t)N * OUT_C;
  float* out_node = out_edge + (size_t)EN;

  char* p = (char*)d_ws;
  auto alloc = [&](size_t bytes) -> char* {
    char* r = p;
    p += (bytes + 255) & ~(size_t)255;
    return r;
  };
  float* h      = (float*)alloc((size_t)N * OUT_C * 4);
  float* ai     = (float*)alloc((size_t)N * 4);
  float* aj     = (float*)alloc((size_t)N * 4);
  u32*   bufA   = (u32*)alloc((size_t)EN * 4);      // CSR items ((tgt&255)<<24 | src)
  u64*   bufB   = (u64*)alloc((size_t)EN * 8);      // staging / src-pairs / agg-pairs
  float* alpha  = (float*)alloc((size_t)EN * 4);    // alpha in CSR order
  u32*   offT   = (u32*)alloc((size_t)(N + 1) * 4);
  u32*   gh     = (u32*)alloc((size_t)NGH * 4);     // tgt hist
  u32*   ghs    = (u32*)alloc((size_t)NGHS * 4);    // src hist
  float* asum   = (float*)alloc((size_t)N * 4);
  u32*   nm     = (u32*)alloc((size_t)N * 4);
  u32*   hist8  = (u32*)alloc(2048 * 4);
  u32*   done   = (u32*)alloc(8 * 4);
  u32*   cnt    = (u32*)alloc(8 * 4);
  u32*   sel    = (u32*)alloc(256);
  u64*   stateT = (u64*)alloc(512 * 8);
  u64*   stateS = (u64*)alloc(1024 * 8);
  u32*   tickets= (u32*)alloc(256);
  u32*   listA  = (u32*)alloc((size_t)N * 4);
  u32*   listB  = (u32*)alloc((size_t)N * 4);

  u32 kSel = (u32)((N + 1) / 2);
  int chunk = (EN + RB - 1) / RB;
  int gRow = (N + GROWS - 1) / GROWS;   // 782
  int gN = (N + 255) / 256;
  int gE = (EN + 255) / 256;
  int gNode8 = (N + 7) / 8;

  k_gemm<<<gRow, 128, 0, stream>>>(x, w, att, h, ai, aj, N);

  // ---- partition by target -> bufA = CSR, offT; fused state init ----
  k_rhist_t<<<RB, 256, 0, stream>>>(tgt, E, EN, chunk, gh, hist8, done, sel, cnt, kSel,
                                    stateT, stateS, tickets);
  k_scan<<<(NGH + 255) / 256, 256, 0, stream>>>(gh, NGH, &tickets[0], stateT);
  k_rscatter_t<<<RB, 256, 0, stream>>>(src, tgt, E, EN, chunk, gh, (u32*)bufB);
  k_rpass2<<<RBINS, 256, 0, stream>>>((u32*)bufB, bufA, gh, ghs, offT, ai, aj, alpha, N, EN);

  // ---- src partition (hist fused in rpass2, same iteration space as scatter) ----
  k_scan<<<(NGHS + 255) / 256, 256, 0, stream>>>(ghs, NGHS, &tickets[1], stateS);
  k_rscatter_s<<<RBINS, 256, 0, stream>>>(bufA, alpha, gh, ghs, bufB, EN);
  k_asum_acc<<<RBINS, 256, 0, stream>>>(bufB, ghs, asum, N, EN);

  // ---- exact top-k: 4 radix passes (fenc) + tie-break finish ----
  k_histpick<<<gN, 256, 0, stream>>>(asum, nullptr, nullptr, nullptr, nullptr,
                                     hist8, done, sel, N, 0, gN);
  k_histpick<<<gN, 256, 0, stream>>>(asum, nullptr, nullptr, listA, &cnt[1],
                                     hist8, done, sel, N, 1, gN);
  k_histpick<<<gN, 256, 0, stream>>>(asum, listA, &cnt[1], listB, &cnt[2],
                                     hist8, done, sel, N, 2, gN);
  k_histpick<<<gN, 256, 0, stream>>>(asum, listB, &cnt[2], listA, &cnt[3],
                                     hist8, done, sel, N, 3, gN);
  k_finish<<<1, 256, 0, stream>>>(asum, listA, &cnt[3], sel);

  k_node_mask<<<gN, 256, 0, stream>>>(asum, sel, nm, out_node, N);
  k_mask<<<gE, 256, 0, stream>>>(src, tgt, nm, bufA, alpha, out_edge, bufB, E, EN);
  k_aggregate<<<gNode8, 256, 0, stream>>>(offT, bufB, h, nm, out, N);
}

// Round 9
// 373.667 us; speedup vs baseline: 2.1644x; 2.1644x over previous
//
#include <hip/hip_runtime.h>
#include <stdint.h>

#define IN_C 128
#define OUT_C 64
#define NEG_SLOPE 0.2f
#define RB 256      // blocks in coarse-partition kernels
#define RBINS 512   // coarse bins (node>>8, node<131072)
#define STAGE 8192  // per-bucket LDS staging capacity
#define NGH (RBINS * RB)       // 131072 (tgt histogram)
#define NGHS (RBINS * RBINS)   // 262144 (src histogram)
#define KC 16                  // gemm k-chunk
#define GROWS 128              // gemm row tile

typedef unsigned int u32;
typedef unsigned long long u64;

// ---------------- helpers ----------------
__device__ __forceinline__ u32 fenc(float f) {
  u32 u = __float_as_uint(f);
  return (u & 0x80000000u) ? ~u : (u | 0x80000000u);
}
__device__ __forceinline__ u64 key64(float v, int i) {
  return (((u64)fenc(v)) << 32) | (u64)(0xffffffffu - (u32)i);
}

// ---------------- h = x @ W + fused ai/aj epilogue ----------------
// 128-row tile, 128 threads, 8x8/thread. KC=16. LDS 40KB; grid 782 (~3 blocks/CU).
__global__ __launch_bounds__(128) void k_gemm(const float* __restrict__ x,
                                              const float* __restrict__ w,
                                              const float* __restrict__ att,
                                              float* __restrict__ h,
                                              float* __restrict__ ai, float* __restrict__ aj,
                                              int N) {
  __shared__ float sw[IN_C * OUT_C];   // 32 KB
  __shared__ float sx[KC * GROWS];     // 8 KB
  int tid = threadIdx.x;
  int rbase = blockIdx.x * GROWS;

  for (int i = tid; i < (IN_C * OUT_C) / 4; i += 128)
    ((float4*)sw)[i] = ((const float4*)w)[i];

  int cg = tid & 7, rg = tid >> 3;
  int c0 = cg * 8, r0 = rg * 8;
  float acc[8][8];
#pragma unroll
  for (int i = 0; i < 8; i++)
#pragma unroll
    for (int j = 0; j < 8; j++) acc[i][j] = 0.f;

  for (int kb = 0; kb < IN_C; kb += KC) {
    __syncthreads();
    {
      int grow = rbase + tid;
      float4 v0 = make_float4(0.f,0.f,0.f,0.f), v1 = v0, v2 = v0, v3 = v0;
      if (grow < N) {
        const float4* xp = (const float4*)&x[(size_t)grow * IN_C + kb];
        v0 = xp[0]; v1 = xp[1]; v2 = xp[2]; v3 = xp[3];
      }
      sx[ 0*GROWS + tid] = v0.x; sx[ 1*GROWS + tid] = v0.y;
      sx[ 2*GROWS + tid] = v0.z; sx[ 3*GROWS + tid] = v0.w;
      sx[ 4*GROWS + tid] = v1.x; sx[ 5*GROWS + tid] = v1.y;
      sx[ 6*GROWS + tid] = v1.z; sx[ 7*GROWS + tid] = v1.w;
      sx[ 8*GROWS + tid] = v2.x; sx[ 9*GROWS + tid] = v2.y;
      sx[10*GROWS + tid] = v2.z; sx[11*GROWS + tid] = v2.w;
      sx[12*GROWS + tid] = v3.x; sx[13*GROWS + tid] = v3.y;
      sx[14*GROWS + tid] = v3.z; sx[15*GROWS + tid] = v3.w;
    }
    __syncthreads();
#pragma unroll
    for (int kl = 0; kl < KC; ++kl) {
      int kg = kb + kl;
      float xr[8], wv[8];
      *(float4*)&xr[0] = *(const float4*)&sx[kl * GROWS + r0];
      *(float4*)&xr[4] = *(const float4*)&sx[kl * GROWS + r0 + 4];
      *(float4*)&wv[0] = *(const float4*)&sw[kg * OUT_C + c0];
      *(float4*)&wv[4] = *(const float4*)&sw[kg * OUT_C + c0 + 4];
#pragma unroll
      for (int i = 0; i < 8; ++i)
#pragma unroll
        for (int j = 0; j < 8; ++j)
          acc[i][j] += xr[i] * wv[j];
    }
  }

  float pi[8], pj[8];
#pragma unroll
  for (int i = 0; i < 8; ++i) { pi[i] = 0.f; pj[i] = 0.f; }
#pragma unroll
  for (int j = 0; j < 8; ++j) {
    float a0 = att[c0 + j], a1 = att[OUT_C + c0 + j];
#pragma unroll
    for (int i = 0; i < 8; ++i) {
      pi[i] += acc[i][j] * a0;
      pj[i] += acc[i][j] * a1;
    }
  }
#pragma unroll
  for (int o = 1; o < 8; o <<= 1) {
#pragma unroll
    for (int i = 0; i < 8; ++i) {
      pi[i] += __shfl_xor(pi[i], o);
      pj[i] += __shfl_xor(pj[i], o);
    }
  }
#pragma unroll
  for (int i = 0; i < 8; ++i) {
    int row = rbase + r0 + i;
    if (row < N) {
      *(float4*)&h[(size_t)row * OUT_C + c0]     = make_float4(acc[i][0], acc[i][1], acc[i][2], acc[i][3]);
      *(float4*)&h[(size_t)row * OUT_C + c0 + 4] = make_float4(acc[i][4], acc[i][5], acc[i][6], acc[i][7]);
      if (cg == 0) { ai[row] = pi[i]; aj[row] = pj[i]; }
    }
  }
}

// ---------------- coarse hist by tgt>>8 + fused select-state init ----------------
__global__ __launch_bounds__(256) void k_rhist_t(const int* __restrict__ tgt,
                                                 int E, int EN, int chunk, u32* __restrict__ gh,
                                                 u32* __restrict__ hist8, u32* __restrict__ done,
                                                 u32* __restrict__ sel, u32* __restrict__ cnt, u32 k) {
  __shared__ u32 lh[RBINS];
  int tid = threadIdx.x, b = blockIdx.x;
  if (b == 0) {
    for (int i = tid; i < 2048; i += 256) hist8[i] = 0u;
    if (tid < 8) { done[tid] = 0u; cnt[tid] = 0u; }
    if (tid == 0) { sel[0] = 0u; sel[1] = 0u; sel[2] = k; sel[3] = 0u; }
  }
  for (int d = tid; d < RBINS; d += 256) lh[d] = 0u;
  __syncthreads();
  int lo = b * chunk, hi = min(lo + chunk, EN);
  for (int e = lo + tid; e < hi; e += 256) {
    int t = (e < E) ? tgt[e] : e - E;
    atomicAdd(&lh[((u32)t) >> 8], 1u);
  }
  __syncthreads();
  for (int d = tid; d < RBINS; d += 256) gh[d * RB + b] = lh[d];
}

// ---------------- 3-kernel exclusive scan (measured cheap; lookback scan was 320us — reverted) ----------------
__global__ __launch_bounds__(256) void k_scanA(const u32* __restrict__ in, u32* __restrict__ out,
                                               u32* __restrict__ bsum, int n) {
  __shared__ u32 s[256];
  int i = blockIdx.x * 256 + threadIdx.x;
  u32 v = (i < n) ? in[i] : 0u;
  s[threadIdx.x] = v;
  __syncthreads();
  for (int o = 1; o < 256; o <<= 1) {
    u32 t = (threadIdx.x >= (unsigned)o) ? s[threadIdx.x - o] : 0u;
    __syncthreads();
    s[threadIdx.x] += t;
    __syncthreads();
  }
  if (i < n) out[i] = s[threadIdx.x] - v;
  if (threadIdx.x == 255) bsum[blockIdx.x] = s[255];
}

__global__ __launch_bounds__(1024) void k_scanB(u32* __restrict__ bsum, int nb) {
  __shared__ u32 s[1024];
  int tid = threadIdx.x;
  u32 v = (tid < nb) ? bsum[tid] : 0u;
  s[tid] = v;
  __syncthreads();
  for (int o = 1; o < 1024; o <<= 1) {
    u32 t = (tid >= o) ? s[tid - o] : 0u;
    __syncthreads();
    s[tid] += t;
    __syncthreads();
  }
  if (tid < nb) bsum[tid] = s[tid] - v;
}

__global__ __launch_bounds__(256) void k_scanC(u32* __restrict__ out, const u32* __restrict__ bsum, int n) {
  int i = blockIdx.x * 256 + threadIdx.x;
  if (i < n) out[i] += bsum[blockIdx.x];
}

// ---------------- coarse scatter by tgt>>8: u32 items ((tgt&255)<<24 | src) ----------------
__global__ __launch_bounds__(256) void k_rscatter_t(const int* __restrict__ src, const int* __restrict__ tgt,
                                                    int E, int EN, int chunk,
                                                    const u32* __restrict__ gh, u32* __restrict__ bufB) {
  __shared__ u32 cnt[RBINS];
  int tid = threadIdx.x, b = blockIdx.x;
  for (int d = tid; d < RBINS; d += 256) cnt[d] = gh[d * RB + b];
  __syncthreads();
  int lo = b * chunk, hi = min(lo + chunk, EN);
  for (int e = lo + tid; e < hi; e += 256) {
    int s, t;
    if (e < E) { s = src[e]; t = tgt[e]; } else { s = t = e - E; }
    u32 p = atomicAdd(&cnt[((u32)t) >> 8], 1u);
    bufB[p] = (((u32)t & 255u) << 24) | (u32)s;
  }
}

// ---------------- fine partition + CSR offsets + fused src>>8 hist + FUSED SOFTMAX ----
__global__ __launch_bounds__(256) void k_rpass2(const u32* __restrict__ in, u32* __restrict__ out,
                                                const u32* __restrict__ gh, u32* __restrict__ ghs,
                                                u32* __restrict__ offT,
                                                const float* __restrict__ ai, const float* __restrict__ aj,
                                                float* __restrict__ alpha,
                                                int N, int EN) {
  __shared__ u32 hist[256];
  __shared__ u32 sc[256];
  __shared__ u32 lhs[RBINS];
  __shared__ u32 stage[STAGE];
  int tid = threadIdx.x, d = blockIdx.x;
  u32 start = gh[d * RB];
  u32 end = (d < RBINS - 1) ? gh[(d + 1) * RB] : (u32)EN;
  int sz = (int)(end - start);
  hist[tid] = 0u;
  for (int dd = tid; dd < RBINS; dd += 256) lhs[dd] = 0u;
  __syncthreads();
  for (u32 p = start + tid; p < end; p += 256) {
    u32 it = in[p];
    atomicAdd(&hist[it >> 24], 1u);
    atomicAdd(&lhs[(it & 0xffffffu) >> 8], 1u);
  }
  __syncthreads();
  for (int dd = tid; dd < RBINS; dd += 256) ghs[dd * RBINS + d] = lhs[dd];
  u32 hv = hist[tid];
  sc[tid] = hv;
  __syncthreads();
  for (int o = 1; o < 256; o <<= 1) {
    u32 t = (tid >= o) ? sc[tid - o] : 0u;
    __syncthreads();
    sc[tid] += t;
    __syncthreads();
  }
  u32 excl = sc[tid] - hv;
  int node = (d << 8) + tid;
  if (node < N) offT[node] = start + excl;
  if (node == 0) offT[N] = (u32)EN;
  hist[tid] = excl;
  __syncthreads();
  bool staged = (sz <= STAGE);
  for (u32 p = start + tid; p < end; p += 256) {
    u32 it = in[p];
    u32 lp = atomicAdd(&hist[it >> 24], 1u);
    if (staged) stage[lp] = it;
    else out[start + lp] = it;
  }
  __syncthreads();
  if (staged)
    for (int i = tid; i < sz; i += 256) out[start + i] = stage[i];
  __syncthreads();
  if (node < N) {
    int lb = (tid > 0) ? (int)sc[tid - 1] : 0;
    int le = (int)sc[tid];
    float an = ai[node];
    float mx = -1e30f;
    for (int i = lb; i < le; ++i) {
      u32 it = staged ? stage[i] : out[start + i];
      float a = an + aj[it & 0xffffffu];
      a = a > 0.f ? a : NEG_SLOPE * a;
      mx = fmaxf(mx, a);
      if (staged) stage[i] = __float_as_uint(a);
    }
    float sm = 0.f;
    for (int i = lb; i < le; ++i) {
      float a;
      if (staged) a = __uint_as_float(stage[i]);
      else {
        u32 it = out[start + i];
        a = an + aj[it & 0xffffffu];
        a = a > 0.f ? a : NEG_SLOPE * a;
      }
      float v = expf(a - mx);
      sm += v;
      if (staged) stage[i] = __float_as_uint(v);
      else alpha[start + i] = v;
    }
    float inv = 1.f / (sm + 1e-16f);
    for (int i = lb; i < le; ++i) {
      float v = staged ? __uint_as_float(stage[i]) : alpha[start + i];
      alpha[start + i] = v * inv;
    }
  }
}

// ---------------- scatter by src>>8 over the SAME per-bucket ranges as k_rpass2 ----------------
__global__ __launch_bounds__(256) void k_rscatter_s(const u32* __restrict__ csr,
                                                    const float* __restrict__ alpha,
                                                    const u32* __restrict__ gh, const u32* __restrict__ ghs,
                                                    u64* __restrict__ bufB, int EN) {
  __shared__ u32 cnt[RBINS];
  int tid = threadIdx.x, d = blockIdx.x;
  for (int dd = tid; dd < RBINS; dd += 256) cnt[dd] = ghs[dd * RBINS + d];
  __syncthreads();
  u32 start = gh[d * RB];
  u32 end = (d < RBINS - 1) ? gh[(d + 1) * RB] : (u32)EN;
  for (u32 e = start + tid; e < end; e += 256) {
    u32 s = csr[e] & 0xffffffu;
    u32 p = atomicAdd(&cnt[s >> 8], 1u);
    bufB[p] = (((u64)(s & 255u)) << 32) | __float_as_uint(alpha[e]);
  }
}

// ---------------- per-bucket alpha_sum accumulation (LDS fp bins) ----------------
__global__ __launch_bounds__(256) void k_asum_acc(const u64* __restrict__ bufB,
                                                  const u32* __restrict__ ghs,
                                                  float* __restrict__ asum, int N, int EN) {
  __shared__ float sums[256];
  int tid = threadIdx.x, d = blockIdx.x;
  u32 start = ghs[d * RBINS];
  u32 end = (d < RBINS - 1) ? ghs[(d + 1) * RBINS] : (u32)EN;
  sums[tid] = 0.f;
  __syncthreads();
  for (u32 p = start + tid; p < end; p += 256) {
    u64 it = bufB[p];
    atomicAdd(&sums[(u32)(it >> 32)], __uint_as_float((u32)it));
  }
  __syncthreads();
  int node = d * 256 + tid;
  if (node < N) asum[node] = sums[tid];
}

// ---------------- fused radix-select pass: hist + append + last-block pick ----------------
__global__ __launch_bounds__(256) void k_histpick(const float* __restrict__ asum,
                                                  const u32* __restrict__ list_in, const u32* __restrict__ cnt_in,
                                                  u32* __restrict__ list_out, u32* __restrict__ cnt_out,
                                                  u32* __restrict__ hist8, u32* __restrict__ done,
                                                  u32* __restrict__ sel, int N, int pass, int nblk) {
  __shared__ u32 lh[256];
  __shared__ u32 sres;
  __shared__ u32 s[256];
  int tid = threadIdx.x;
  lh[tid] = 0u;
  __syncthreads();
  u64 prefix = ((const u64*)sel)[0];
  int shift = 56 - 8 * pass;
  int n = list_in ? (int)*cnt_in : N;
  int i = blockIdx.x * 256 + tid;
  if (i < n) {
    int idx = list_in ? (int)list_in[i] : i;
    u64 k = key64(asum[idx], idx);
    bool ok = (pass == 0) || ((k >> (shift + 8)) == prefix);
    if (ok) {
      atomicAdd(&lh[(u32)(k >> shift) & 255u], 1u);
      if (list_out) {
        u32 p = atomicAdd(cnt_out, 1u);
        list_out[p] = (u32)idx;
      }
    }
  }
  __syncthreads();
  if (lh[tid]) atomicAdd(&hist8[pass * 256 + tid], lh[tid]);
  __syncthreads();
  if (tid == 0)
    sres = __hip_atomic_fetch_add(&done[pass], 1u, __ATOMIC_ACQ_REL, __HIP_MEMORY_SCOPE_AGENT);
  __syncthreads();
  if (sres == (u32)(nblk - 1)) {
    u32 krem = sel[2];
    u32 hv = __hip_atomic_load(&hist8[pass * 256 + (255 - tid)], __ATOMIC_RELAXED,
                               __HIP_MEMORY_SCOPE_AGENT);
    s[tid] = hv;
    __syncthreads();
    for (int o = 1; o < 256; o <<= 1) {
      u32 t = (tid >= o) ? s[tid - o] : 0u;
      __syncthreads();
      s[tid] += t;
      __syncthreads();
    }
    u32 cum = s[tid], prev = (tid > 0) ? s[tid - 1] : 0u;
    if (cum >= krem && prev < krem) {
      int dsel = 255 - tid;
      ((u64*)sel)[0] = (prefix << 8) | (u64)(u32)dsel;
      sel[2] = krem - prev;
    }
  }
}

// ---------------- finish select: fenc fixed after 4 passes; rank-select index ties ----------------
__global__ __launch_bounds__(256) void k_finish(const float* __restrict__ asum,
                                                const u32* __restrict__ list, const u32* __restrict__ cntp,
                                                u32* __restrict__ sel) {
  __shared__ u64 keys[2048];
  __shared__ u32 cc;
  int tid = threadIdx.x;
  if (tid == 0) cc = 0u;
  __syncthreads();
  int n = (int)*cntp;
  u32 fsel = (u32)((const u64*)sel)[0];
  u32 krem = sel[2];
  for (int i = tid; i < n; i += 256) {
    int idx = (int)list[i];
    u64 k = key64(asum[idx], idx);
    if ((u32)(k >> 32) == fsel) {
      u32 p = atomicAdd(&cc, 1u);
      if (p < 2048) keys[p] = k;
    }
  }
  __syncthreads();
  int C = (int)min(cc, 2048u);
  for (int i = tid; i < C; i += 256) {
    u64 k = keys[i];
    u32 rank = 0;
    for (int j = 0; j < C; ++j)
      if (keys[j] > k) rank++;
    if (rank == krem - 1) ((u64*)sel)[0] = k;
  }
}

// ---------------- node mask ----------------
__global__ __launch_bounds__(256) void k_node_mask(const float* __restrict__ asum,
                                                   const u32* __restrict__ sel,
                                                   u32* __restrict__ nm,
                                                   float* __restrict__ out_node, int N) {
  int i = blockIdx.x * 256 + threadIdx.x;
  if (i >= N) return;
  u64 T = ((const u64*)sel)[0];
  bool m = key64(asum[i], i) >= T;
  nm[i] = m ? 1u : 0u;
  out_node[i] = m ? 1.f : 0.f;
}

// ---------------- fused: raw-order edge mask + CSR-order premasked (src,alpha) pairs ----------------
__global__ __launch_bounds__(256) void k_mask(const int* __restrict__ src, const int* __restrict__ tgt,
                                              const u32* __restrict__ nm,
                                              const u32* __restrict__ csr, const float* __restrict__ alpha,
                                              float* __restrict__ out_edge, u64* __restrict__ pair,
                                              int E, int EN) {
  int e = blockIdx.x * 256 + threadIdx.x;
  if (e >= EN) return;
  int s, t;
  if (e < E) { s = src[e]; t = tgt[e]; } else { s = t = e - E; }
  out_edge[e] = (nm[s] && nm[t]) ? 1.f : 0.f;
  u32 sp = csr[e] & 0xffffffu;
  u32 ab = nm[sp] ? __float_as_uint(alpha[e]) : 0u;
  pair[e] = (((u64)sp) << 32) | ab;
}

// ---------------- aggregate: branchless, 2 nodes/wave, 8-deep pipeline ----------------
__global__ __launch_bounds__(256) void k_aggregate(const u32* __restrict__ off,
                                                   const u64* __restrict__ pair,
                                                   const float* __restrict__ h,
                                                   const u32* __restrict__ nm,
                                                   float* __restrict__ out, int N) {
  int node = blockIdx.x * 8 + (threadIdx.x >> 5);
  int sub = threadIdx.x & 31;
  int g = sub >> 4;
  int c = sub & 15;
  if (node >= N) return;
  float4 acc = make_float4(0.f, 0.f, 0.f, 0.f);
  if (nm[node]) {
    u32 b = off[node], e2 = off[node + 1];
    for (u32 p0 = b; p0 < e2; p0 += 16) {
      u64 pr[8];
      float av[8];
      u32 sv[8];
#pragma unroll
      for (int q = 0; q < 8; ++q) {
        u32 p = p0 + q * 2 + (u32)g;
        bool ok = p < e2;
        pr[q] = pair[ok ? p : b];
        av[q] = ok ? __uint_as_float((u32)pr[q]) : 0.f;
        sv[q] = (u32)(pr[q] >> 32);
      }
      float4 hv[8];
#pragma unroll
      for (int q = 0; q < 8; ++q)
        hv[q] = *(const float4*)&h[(size_t)sv[q] * OUT_C + c * 4];
#pragma unroll
      for (int q = 0; q < 8; ++q) {
        acc.x += av[q] * hv[q].x;
        acc.y += av[q] * hv[q].y;
        acc.z += av[q] * hv[q].z;
        acc.w += av[q] * hv[q].w;
      }
    }
    acc.x += __shfl_xor(acc.x, 16);
    acc.y += __shfl_xor(acc.y, 16);
    acc.z += __shfl_xor(acc.z, 16);
    acc.w += __shfl_xor(acc.w, 16);
  }
  if (g == 0)
    *(float4*)&out[(size_t)node * OUT_C + c * 4] = acc;
}

// ---------------- launch ----------------
extern "C" void kernel_launch(void* const* d_in, const int* in_sizes, int n_in,
                              void* d_out, int out_size, void* d_ws, size_t ws_size,
                              hipStream_t stream) {
  const float* x   = (const float*)d_in[0];
  const float* w   = (const float*)d_in[1];
  const float* att = (const float*)d_in[2];
  const int*   ei  = (const int*)d_in[3];

  int N = in_sizes[0] / IN_C;
  int E = in_sizes[3] / 2;
  int EN = E + N;
  const int* src = ei;
  const int* tgt = ei + E;

  float* out      = (float*)d_out;
  float* out_edge = out + (size_t)N * OUT_C;
  float* out_node = out_edge + (size_t)EN;

  char* p = (char*)d_ws;
  auto alloc = [&](size_t bytes) -> char* {
    char* r = p;
    p += (bytes + 255) & ~(size_t)255;
    return r;
  };
  float* h      = (float*)alloc((size_t)N * OUT_C * 4);
  float* ai     = (float*)alloc((size_t)N * 4);
  float* aj     = (float*)alloc((size_t)N * 4);
  u32*   bufA   = (u32*)alloc((size_t)EN * 4);      // CSR items ((tgt&255)<<24 | src)
  u64*   bufB   = (u64*)alloc((size_t)EN * 8);      // staging / src-pairs / agg-pairs
  float* alpha  = (float*)alloc((size_t)EN * 4);    // alpha in CSR order
  u32*   offT   = (u32*)alloc((size_t)(N + 1) * 4);
  u32*   gh     = (u32*)alloc((size_t)NGH * 4);     // tgt hist
  u32*   ghs    = (u32*)alloc((size_t)NGHS * 4);    // src hist
  u32*   bsum   = (u32*)alloc(2048 * 4);
  float* asum   = (float*)alloc((size_t)N * 4);
  u32*   nm     = (u32*)alloc((size_t)N * 4);
  u32*   hist8  = (u32*)alloc(2048 * 4);
  u32*   done   = (u32*)alloc(8 * 4);
  u32*   cnt    = (u32*)alloc(8 * 4);
  u32*   sel    = (u32*)alloc(256);
  u32*   listA  = (u32*)alloc((size_t)N * 4);
  u32*   listB  = (u32*)alloc((size_t)N * 4);

  u32 kSel = (u32)((N + 1) / 2);
  int chunk = (EN + RB - 1) / RB;
  int nScanT = (NGH + 255) / 256;    // 512
  int nScanS = (NGHS + 255) / 256;   // 1024
  int gRow = (N + GROWS - 1) / GROWS;
  int gN = (N + 255) / 256;
  int gE = (EN + 255) / 256;
  int gNode8 = (N + 7) / 8;

  k_gemm<<<gRow, 128, 0, stream>>>(x, w, att, h, ai, aj, N);

  // ---- partition by target -> bufA = CSR, offT; fused select-state init ----
  k_rhist_t<<<RB, 256, 0, stream>>>(tgt, E, EN, chunk, gh, hist8, done, sel, cnt, kSel);
  k_scanA<<<nScanT, 256, 0, stream>>>(gh, gh, bsum, NGH);
  k_scanB<<<1, 1024, 0, stream>>>(bsum, nScanT);
  k_scanC<<<nScanT, 256, 0, stream>>>(gh, bsum, NGH);
  k_rscatter_t<<<RB, 256, 0, stream>>>(src, tgt, E, EN, chunk, gh, (u32*)bufB);
  k_rpass2<<<RBINS, 256, 0, stream>>>((u32*)bufB, bufA, gh, ghs, offT, ai, aj, alpha, N, EN);

  // ---- src partition (hist fused in rpass2, same iteration space as scatter) ----
  k_scanA<<<nScanS, 256, 0, stream>>>(ghs, ghs, bsum, NGHS);
  k_scanB<<<1, 1024, 0, stream>>>(bsum, nScanS);
  k_scanC<<<nScanS, 256, 0, stream>>>(ghs, bsum, NGHS);
  k_rscatter_s<<<RBINS, 256, 0, stream>>>(bufA, alpha, gh, ghs, bufB, EN);
  k_asum_acc<<<RBINS, 256, 0, stream>>>(bufB, ghs, asum, N, EN);

  // ---- exact top-k: 4 radix passes (fenc) + tie-break finish ----
  k_histpick<<<gN, 256, 0, stream>>>(asum, nullptr, nullptr, nullptr, nullptr,
                                     hist8, done, sel, N, 0, gN);
  k_histpick<<<gN, 256, 0, stream>>>(asum, nullptr, nullptr, listA, &cnt[1],
                                     hist8, done, sel, N, 1, gN);
  k_histpick<<<gN, 256, 0, stream>>>(asum, listA, &cnt[1], listB, &cnt[2],
                                     hist8, done, sel, N, 2, gN);
  k_histpick<<<gN, 256, 0, stream>>>(asum, listB, &cnt[2], listA, &cnt[3],
                                     hist8, done, sel, N, 3, gN);
  k_finish<<<1, 256, 0, stream>>>(asum, listA, &cnt[3], sel);

  k_node_mask<<<gN, 256, 0, stream>>>(asum, sel, nm, out_node, N);
  k_mask<<<gE, 256, 0, stream>>>(src, tgt, nm, bufA, alpha, out_edge, bufB, E, EN);
  k_aggregate<<<gNode8, 256, 0, stream>>>(offT, bufB, h, nm, out, N);
}